// Round 5
// baseline (408.426 us; speedup 1.0000x reference)
//
#include <hip/hip_runtime.h>
#include <math.h>

#define PI_F      3.141592653f
#define TWO_PI_F  6.283185306f
#define HALF_PI_F 1.5707963265f
#define IOU_THR_F 0.1f
#define ITILE     16

typedef unsigned long long u64;

__device__ __forceinline__ float limit_period_f(float v) {
    return v - floorf(v / TWO_PI_F + 0.5f) * TWO_PI_F;
}

__device__ __forceinline__ u64 shfl_u64(u64 v, int src) {
    unsigned int lo = (unsigned int)(v & 0xffffffffull);
    unsigned int hi = (unsigned int)(v >> 32);
    lo = __shfl((int)lo, src);
    hi = __shfl((int)hi, src);
    return ((u64)hi << 32) | (u64)lo;
}

__device__ __forceinline__ u64 shfl_xor_u64(u64 v, int mask) {
    unsigned int lo = (unsigned int)(v & 0xffffffffull);
    unsigned int hi = (unsigned int)(v >> 32);
    lo = __shfl_xor((int)lo, mask);
    hi = __shfl_xor((int)hi, mask);
    return ((u64)hi << 32) | (u64)lo;
}

// ---------------- Kernel 1: per-box prep (lo/hi/vol/dir) ----------------
__global__ void prep_kernel(const float* __restrict__ boxes, int n,
                            float* __restrict__ lox, float* __restrict__ loy, float* __restrict__ loz,
                            float* __restrict__ hix, float* __restrict__ hiy, float* __restrict__ hiz,
                            float* __restrict__ vol, float* __restrict__ dir) {
    int j = blockIdx.x * blockDim.x + threadIdx.x;
    if (j >= n) return;
    float b0 = boxes[j*7+0], b1 = boxes[j*7+1], b2 = boxes[j*7+2];
    float b3 = boxes[j*7+3], b4 = boxes[j*7+4], b5 = boxes[j*7+5];
    float b6 = boxes[j*7+6];
    // reference: c = boxes[:, :3]; d = boxes[:, [5,4,3]] = (l, w, h)
    lox[j] = b0 - b5*0.5f; hix[j] = b0 + b5*0.5f;
    loy[j] = b1 - b4*0.5f; hiy[j] = b1 + b4*0.5f;
    loz[j] = b2 - b3*0.5f; hiz[j] = b2 + b3*0.5f;
    vol[j] = (b5*b4)*b3;                   // d.prod(-1) order: l*w*h
    dir[j] = limit_period_f(b6);
}

// ---------------- Kernel 2: adjacency bit-matrix, i-tiled, column-word layout -
// adjC[(size_t)w * n + i] = word w of row i (bits for nodes 64w..64w+63)
__global__ void adj_kernel(const float* __restrict__ lox, const float* __restrict__ loy,
                           const float* __restrict__ loz, const float* __restrict__ hix,
                           const float* __restrict__ hiy, const float* __restrict__ hiz,
                           const float* __restrict__ vol,
                           u64* __restrict__ adjC, int n, int words) {
    __shared__ float iS[7][ITILE];
    int ib = blockIdx.x * ITILE;
    int tid = threadIdx.x;              // 256 = 4 waves
    if (tid < ITILE) {
        int i = ib + tid;
        if (i < n) {
            iS[0][tid] = lox[i]; iS[1][tid] = loy[i]; iS[2][tid] = loz[i];
            iS[3][tid] = hix[i]; iS[4][tid] = hiy[i]; iS[5][tid] = hiz[i];
            iS[6][tid] = vol[i];
        }
    }
    __syncthreads();
    int lane = tid & 63, wv = tid >> 6;
    int ntile = (n + 255) >> 8;
    for (int t = 0; t < ntile; ++t) {
        int j = (t << 8) + tid;
        bool jin = j < n;
        float ljx=0, ljy=0, ljz=0, hjx=0, hjy=0, hjz=0, vj=0;
        if (jin) {
            ljx = lox[j]; ljy = loy[j]; ljz = loz[j];
            hjx = hix[j]; hjy = hiy[j]; hjz = hiz[j];
            vj  = vol[j];
        }
        int wj = (t << 2) + wv;         // uniform across the wave
        u64 myMask = 0;
        for (int ii = 0; ii < ITILE; ++ii) {
            bool pred = false;
            if (jin && (ib + ii) < n) {
                float ix = fminf(iS[3][ii], hjx) - fmaxf(iS[0][ii], ljx); ix = fmaxf(ix, 0.0f);
                float iy = fminf(iS[4][ii], hjy) - fmaxf(iS[1][ii], ljy); iy = fmaxf(iy, 0.0f);
                float iz = fminf(iS[5][ii], hjz) - fmaxf(iS[2][ii], ljz); iz = fmaxf(iz, 0.0f);
                float inter = (ix*iy)*iz;
                float u = fmaxf(iS[6][ii] + vj - inter, 1e-8f);
                pred = (inter / u) > IOU_THR_F;
            }
            u64 mk = __ballot(pred);
            if (lane == ii) myMask = mk;
        }
        if (lane < ITILE && (ib + lane) < n && wj < words)
            adjC[(size_t)wj * n + (ib + lane)] = myMask;
    }
}

// ---------------- Kernel 3: word-sequential greedy MIS, pull-based, wave0-only -
// seed(i) <=> no earlier neighbor of i is a seed (lexicographically-first MIS).
// Waves 1-3 prewarm adjC into this XCD's L2 concurrently (read-only, no barriers).
__global__ void cluster_kernel(const u64* __restrict__ adjC,
                               u64* __restrict__ seedMaskG,
                               int* __restrict__ wordScanG,
                               int* __restrict__ seedListG,
                               int* __restrict__ nclust,
                               int n, int words) {
    __shared__ int seedListS[2048];
    int tid = threadIdx.x;         // 256
    if (tid >= 64) {
        // prewarm: stream the whole bit-matrix into the local L2
        size_t total = (size_t)words * n;
        u64 acc = 0ull;
        for (size_t p = (size_t)(tid - 64); p < total; p += 192) acc |= adjC[p];
        unsigned int alo = (unsigned int)acc, ahi = (unsigned int)(acc >> 32);
        asm volatile("" :: "v"(alo), "v"(ahi));   // keep loads live
        return;
    }
    int lane = tid;                // wave 0: 64 lanes
    u64 A = (lane < n) ? adjC[lane] : 0ull;   // word-0 diagonal block
    int cidBase = 0;
    for (int w = 0; w < words; ++w) {
        // prefetch next diagonal block (independent)
        u64 Anext = 0ull;
        if (w + 1 < words) {
            int node = ((w + 1) << 6) + lane;
            if (node < n) Anext = adjC[(size_t)(w + 1) * n + node];
        }
        // pull eMask: OR of word-w bits over all seeds found so far
        u64 em = 0ull;
        const u64* colw = adjC + (size_t)w * n;
        for (int k = lane; k < cidBase; k += 64) em |= colw[seedListS[k]];
        for (int o = 1; o < 64; o <<= 1) em |= shfl_xor_u64(em, o);
        // in-word greedy (wave-uniform values)
        int base = w << 6;
        int vb = n - base;
        u64 valid = (vb >= 64) ? ~0ull : ((vb <= 0) ? 0ull : ((1ull << vb) - 1ull));
        u64 avail = valid;
        u64 s = 0ull;
        u64 cand = avail & ~em;
        while (cand) {             // iterations = #seeds in this word
            int b = (int)__ffsll(cand) - 1;
            s |= 1ull << b;
            u64 Ab = shfl_u64(A, b);
            avail &= ~Ab;
            u64 himask = (b >= 63) ? 0ull : ~((2ull << b) - 1ull);
            cand = avail & ~em & himask;
        }
        if ((s >> lane) & 1ull) {
            int pos = __popcll(s & ((1ull << lane) - 1ull));
            if (cidBase + pos < 2048) seedListS[cidBase + pos] = base + lane;
            seedListG[cidBase + pos] = base + lane;
        }
        if (lane == 0) { seedMaskG[w] = s; wordScanG[w] = cidBase; }
        cidBase += __popcll(s);    // uniform across lanes
        A = Anext;
    }
    if (lane == 0) *nclust = cidBase;
}

// ---------------- Kernel 4: indices[j] = cid of max-index adjacent seed -------
// 64 independent coalesced loads per node; keep last nonzero word (== highest).
__global__ void indices_kernel(const u64* __restrict__ adjC,
                               const u64* __restrict__ seedMaskG,
                               const int* __restrict__ wordScanG,
                               int* __restrict__ indices, int n, int words) {
    __shared__ u64 sm[64];
    __shared__ int wsS[64];
    int tid = threadIdx.x;  // 256
    if (tid < words) { sm[tid] = seedMaskG[tid]; wsS[tid] = wordScanG[tid]; }
    __syncthreads();
    int j = blockIdx.x * blockDim.x + tid;
    if (j >= n) return;
    int idx = 0;
    for (int w = 0; w < words; ++w) {
        u64 m = adjC[(size_t)w * n + j] & sm[w];   // coalesced across j, independent
        if (m) {
            int b = 63 - (int)__clzll(m);
            u64 incl = (b >= 63) ? ~0ull : ((2ull << b) - 1ull);
            idx = wsS[w] + __popcll(sm[w] & incl);  // inclusive rank = 1-based cid
        }
    }
    indices[j] = idx;
}

// ---------------- Kernel 5: per-cluster fusion (seed-row member gather) -------
__global__ void fusion_kernel(const float* __restrict__ boxes,
                              const float* __restrict__ scores,
                              const int* __restrict__ indices,
                              const float* __restrict__ dir,
                              const int* __restrict__ seedListG,
                              const int* __restrict__ nclust,
                              const u64* __restrict__ adjC,
                              float* __restrict__ fused,
                              float* __restrict__ sfused,
                              int* __restrict__ validArr, int n, int words) {
    int i = blockIdx.x;           // output row; cluster id = i+1
    int lane = threadIdx.x;       // 64 = 1 wave
    int cid = i + 1;
    if (cid > *nclust) {
        if (lane < 7) fused[i*7+lane] = 0.0f;
        if (lane == 0) { sfused[i] = 0.0f; validArr[i] = 0; }
        return;
    }
    __shared__ unsigned short js[256];
    __shared__ float ms[256];
    int s = seedListG[i];
    u64 bits = (lane < words) ? adjC[(size_t)lane * n + s] : 0ull;
    // filter: keep only nodes whose final cluster is cid
    u64 keep = 0ull;
    u64 t = bits;
    while (t) {
        int b = (int)__ffsll(t) - 1;
        t &= t - 1;
        int node = (lane << 6) + b;
        if (indices[node] == cid) keep |= (1ull << b);
    }
    int cnt = __popcll(keep);
    int x = cnt;
    for (int o = 1; o < 64; o <<= 1) {
        int y = __shfl_up(x, o);
        if (lane >= o) x += y;
    }
    int excl = x - cnt;
    int m = __shfl(x, 63);
    int pos = excl;
    t = keep;
    while (t) {
        int b = (int)__ffsll(t) - 1;
        t &= t - 1;
        js[pos++] = (unsigned short)((lane << 6) + b);
    }
    __syncthreads();
    for (int k = lane; k < m; k += 64) ms[k] = scores[js[k]];
    __syncthreads();
    if (lane == 0) {
        if (m == 0) {
            for (int k = 0; k < 7; ++k) fused[i*7+k] = 0.0f;
            sfused[i] = 0.0f; validArr[i] = 0;
        } else {
            // s_sum and argmax (first occurrence of max; js ascending + strict >)
            float ssum = 0.0f, smax = -1e30f; int refj = js[0];
            for (int k = 0; k < m; ++k) {
                float sc = ms[k];
                ssum += sc;
                if (sc > smax) { smax = sc; refj = js[k]; }
            }
            float refdir = dir[refj];
            float denom = fmaxf(ssum, 1e-12f);
            float sgt = 0.0f;
            float cd0=0,cd1=0,cd2=0,cd3=0,cd4=0,cd5=0;
            for (int k = 0; k < m; ++k) {
                int j = js[k];
                float sc = ms[k];
                float d = fabsf(dir[j] - refdir);
                if (d > PI_F) d = TWO_PI_F - d;
                if (d > HALF_PI_F) sgt += sc;
                float wgt = sc / denom;
                cd0 += wgt * boxes[j*7+0];
                cd1 += wgt * boxes[j*7+1];
                cd2 += wgt * boxes[j*7+2];
                cd3 += wgt * boxes[j*7+3];
                cd4 += wgt * boxes[j*7+4];
                cd5 += wgt * boxes[j*7+5];
            }
            float sle = ssum - sgt;
            bool flipGt = (sgt <= sle);
            float ssin = 0.0f, scos = 0.0f;
            for (int k = 0; k < m; ++k) {
                int j = js[k];
                float sc = ms[k];
                float dj = dir[j];
                float d = fabsf(dj - refdir);
                if (d > PI_F) d = TWO_PI_F - d;
                bool gt = d > HALF_PI_F;
                bool flip = flipGt ? gt : !gt;
                float adj_d = limit_period_f(dj + (flip ? PI_F : 0.0f));
                float wgt = sc / denom;
                ssin += sinf(adj_d) * wgt;
                scos += cosf(adj_d) * wgt;
            }
            float theta = atan2f(ssin, scos);
            // s_fused: sort member scores descending, sum s_k^(k+1)
            for (int k = 1; k < m; ++k) {
                float key = ms[k]; int p = k - 1;
                while (p >= 0 && ms[p] < key) { ms[p+1] = ms[p]; --p; }
                ms[p+1] = key;
            }
            float sf = 0.0f;
            for (int k = 0; k < m; ++k) sf += powf(ms[k], (float)(k+1));
            sf = fminf(sf, 1.0f);
            // corners range check
            float c_ = cosf(theta), s_ = sinf(theta);
            float wdim = cd4, ldim = cd5;
            const float xs[4]  = {0.5f, 0.5f, -0.5f, -0.5f};
            const float ys_[4] = {-0.5f, 0.5f, 0.5f, -0.5f};
            bool inr = true;
            for (int c = 0; c < 4; ++c) {
                float cx = ldim * xs[c], cy = wdim * ys_[c];
                float rx = cx*c_ - cy*s_ + cd0;
                float ry = cx*s_ + cy*c_ + cd1;
                inr = inr && (rx > -140.8f) && (rx < 140.8f) && (ry > -40.0f) && (ry < 40.0f);
            }
            fused[i*7+0]=cd0; fused[i*7+1]=cd1; fused[i*7+2]=cd2;
            fused[i*7+3]=cd3; fused[i*7+4]=cd4; fused[i*7+5]=cd5;
            fused[i*7+6]=theta;
            sfused[i] = sf;
            validArr[i] = inr ? 1 : 0;
        }
    }
}

// ---------------- Kernel 6: cumsum + gated output writes ----------------
__global__ void finalize_kernel(const float* __restrict__ fused,
                                const float* __restrict__ sfused,
                                const int* __restrict__ validArr,
                                const int* __restrict__ indices,
                                float* __restrict__ out, int n) {
    __shared__ int newidS[4096];
    __shared__ unsigned char validS[4096];
    __shared__ int scanBuf[1024];
    int tid = threadIdx.x;  // 1024
    int per = (n + 1023) >> 10;  // 4
    int base = tid * per;
    int v[8];
    int sum = 0;
    for (int k = 0; k < per && k < 8; ++k) {
        int j = base + k;
        int vv = (j < n) ? validArr[j] : 0;
        v[k] = vv; sum += vv;
    }
    scanBuf[tid] = sum;
    __syncthreads();
    for (int o = 1; o < 1024; o <<= 1) {
        int val = scanBuf[tid];
        int add = (tid >= o) ? scanBuf[tid - o] : 0;
        __syncthreads();
        scanBuf[tid] = val + add;
        __syncthreads();
    }
    int run = scanBuf[tid] - sum;
    for (int k = 0; k < per && k < 8; ++k) {
        int j = base + k;
        if (j < n) { run += v[k]; newidS[j] = run; validS[j] = (unsigned char)v[k]; }
    }
    __syncthreads();
    float* boxesO  = out;
    float* scoresO = out + (size_t)7*n;
    float* validO  = out + (size_t)8*n;
    float* idxO    = out + (size_t)9*n;
    for (int j = tid; j < n; j += 1024) {
        int vv = validS[j];
        #pragma unroll
        for (int k = 0; k < 7; ++k)
            boxesO[j*7+k] = vv ? fused[j*7+k] : 0.0f;
        scoresO[j] = vv ? sfused[j] : 0.0f;
        validO[j]  = vv ? 1.0f : 0.0f;
        int ind = indices[j];
        int safe = ind - 1; if (safe < 0) safe = 0;
        bool nv = (ind > 0) && (validS[safe] != 0);
        idxO[j] = nv ? (float)newidS[safe] : 0.0f;
    }
}

extern "C" void kernel_launch(void* const* d_in, const int* in_sizes, int n_in,
                              void* d_out, int out_size, void* d_ws, size_t ws_size,
                              hipStream_t stream) {
    const float* boxes  = (const float*)d_in[0];
    const float* scores = (const float*)d_in[1];
    int n = in_sizes[0] / 7;           // 4096
    int words = (n + 63) >> 6;         // 64

    char* ws = (char*)d_ws;
    size_t nf = (size_t)n * sizeof(float);
    size_t off = 0;
    float* lox = (float*)(ws + off); off += nf;
    float* loy = (float*)(ws + off); off += nf;
    float* loz = (float*)(ws + off); off += nf;
    float* hix = (float*)(ws + off); off += nf;
    float* hiy = (float*)(ws + off); off += nf;
    float* hiz = (float*)(ws + off); off += nf;
    float* vol = (float*)(ws + off); off += nf;
    float* dir = (float*)(ws + off); off += nf;
    off = (off + 7) & ~(size_t)7;
    u64* adjC = (u64*)(ws + off);
    off += (size_t)n * words * sizeof(u64);
    u64* seedMask = (u64*)(ws + off); off += 64 * sizeof(u64);
    int* wordScan = (int*)(ws + off); off += 64 * sizeof(int);
    int* seedList = (int*)(ws + off); off += (size_t)n * sizeof(int);
    int* indices  = (int*)(ws + off); off += (size_t)n * sizeof(int);
    float* fused  = (float*)(ws + off); off += (size_t)n * 7 * sizeof(float);
    float* sfused = (float*)(ws + off); off += nf;
    int* validArr = (int*)(ws + off); off += (size_t)n * sizeof(int);
    int* nclust   = (int*)(ws + off); off += sizeof(int);

    prep_kernel<<<(n + 255) / 256, 256, 0, stream>>>(boxes, n, lox, loy, loz,
                                                     hix, hiy, hiz, vol, dir);
    adj_kernel<<<(n + ITILE - 1) / ITILE, 256, 0, stream>>>(lox, loy, loz, hix, hiy, hiz,
                                                            vol, adjC, n, words);
    cluster_kernel<<<1, 256, 0, stream>>>(adjC, seedMask, wordScan, seedList, nclust, n, words);
    indices_kernel<<<(n + 255) / 256, 256, 0, stream>>>(adjC, seedMask, wordScan, indices, n, words);
    fusion_kernel<<<n, 64, 0, stream>>>(boxes, scores, indices, dir, seedList, nclust,
                                        adjC, fused, sfused, validArr, n, words);
    finalize_kernel<<<1, 1024, 0, stream>>>(fused, sfused, validArr, indices,
                                            (float*)d_out, n);
}

// Round 6
// 291.226 us; speedup vs baseline: 1.4024x; 1.4024x over previous
//
#include <hip/hip_runtime.h>
#include <math.h>

#define PI_F      3.141592653f
#define TWO_PI_F  6.283185306f
#define HALF_PI_F 1.5707963265f
#define IOU_THR_F 0.1f
#define ITILE     16

typedef unsigned long long u64;

__device__ __forceinline__ float limit_period_f(float v) {
    return v - floorf(v / TWO_PI_F + 0.5f) * TWO_PI_F;
}

// ---------------- Kernel 1: per-box prep (lo/hi/vol/dir) ----------------
__global__ void prep_kernel(const float* __restrict__ boxes, int n,
                            float* __restrict__ lox, float* __restrict__ loy, float* __restrict__ loz,
                            float* __restrict__ hix, float* __restrict__ hiy, float* __restrict__ hiz,
                            float* __restrict__ vol, float* __restrict__ dir) {
    int j = blockIdx.x * blockDim.x + threadIdx.x;
    if (j >= n) return;
    float b0 = boxes[j*7+0], b1 = boxes[j*7+1], b2 = boxes[j*7+2];
    float b3 = boxes[j*7+3], b4 = boxes[j*7+4], b5 = boxes[j*7+5];
    float b6 = boxes[j*7+6];
    // reference: c = boxes[:, :3]; d = boxes[:, [5,4,3]] = (l, w, h)
    lox[j] = b0 - b5*0.5f; hix[j] = b0 + b5*0.5f;
    loy[j] = b1 - b4*0.5f; hiy[j] = b1 + b4*0.5f;
    loz[j] = b2 - b3*0.5f; hiz[j] = b2 + b3*0.5f;
    vol[j] = (b5*b4)*b3;                   // d.prod(-1) order: l*w*h
    dir[j] = limit_period_f(b6);
}

// ---------------- Kernel 2: adjacency bit-matrix, i-tiled, column-word layout -
// adjC[(size_t)w * n + i] = word w of row i (bits for nodes 64w..64w+63)
__global__ void adj_kernel(const float* __restrict__ lox, const float* __restrict__ loy,
                           const float* __restrict__ loz, const float* __restrict__ hix,
                           const float* __restrict__ hiy, const float* __restrict__ hiz,
                           const float* __restrict__ vol,
                           u64* __restrict__ adjC, int n, int words) {
    __shared__ float iS[7][ITILE];
    int ib = blockIdx.x * ITILE;
    int tid = threadIdx.x;              // 256 = 4 waves
    if (tid < ITILE) {
        int i = ib + tid;
        if (i < n) {
            iS[0][tid] = lox[i]; iS[1][tid] = loy[i]; iS[2][tid] = loz[i];
            iS[3][tid] = hix[i]; iS[4][tid] = hiy[i]; iS[5][tid] = hiz[i];
            iS[6][tid] = vol[i];
        }
    }
    __syncthreads();
    int lane = tid & 63, wv = tid >> 6;
    int ntile = (n + 255) >> 8;
    for (int t = 0; t < ntile; ++t) {
        int j = (t << 8) + tid;
        bool jin = j < n;
        float ljx=0, ljy=0, ljz=0, hjx=0, hjy=0, hjz=0, vj=0;
        if (jin) {
            ljx = lox[j]; ljy = loy[j]; ljz = loz[j];
            hjx = hix[j]; hjy = hiy[j]; hjz = hiz[j];
            vj  = vol[j];
        }
        int wj = (t << 2) + wv;         // uniform across the wave
        u64 myMask = 0;
        for (int ii = 0; ii < ITILE; ++ii) {
            bool pred = false;
            if (jin && (ib + ii) < n) {
                float ix = fminf(iS[3][ii], hjx) - fmaxf(iS[0][ii], ljx); ix = fmaxf(ix, 0.0f);
                float iy = fminf(iS[4][ii], hjy) - fmaxf(iS[1][ii], ljy); iy = fmaxf(iy, 0.0f);
                float iz = fminf(iS[5][ii], hjz) - fmaxf(iS[2][ii], ljz); iz = fmaxf(iz, 0.0f);
                float inter = (ix*iy)*iz;
                float u = fmaxf(iS[6][ii] + vj - inter, 1e-8f);
                pred = (inter / u) > IOU_THR_F;
            }
            u64 mk = __ballot(pred);
            if (lane == ii) myMask = mk;
        }
        if (lane < ITILE && (ib + lane) < n && wj < words)
            adjC[(size_t)wj * n + (ib + lane)] = myMask;
    }
}

// ---------------- Kernel 3: connected components, LDS union-find (1 WG) -------
// Lock-free hook-to-min UF; final root of each node = component minimum
// (deterministic regardless of internal race interleaving).
__global__ __launch_bounds__(1024) void ccuf_kernel(const u64* __restrict__ adjC,
                                                    int* __restrict__ parentG,
                                                    int n, int words) {
    __shared__ int par[4096];
    int tid = threadIdx.x;
    for (int i = tid; i < n; i += 1024) par[i] = i;
    __syncthreads();
    volatile int* vp = (volatile int*)par;
    for (int w = 0; w < words; ++w) {
        int base = w << 6;
        for (int i = tid; i < n; i += 1024) {
            if (base + 63 <= i) continue;          // upper triangle only (j > i)
            u64 bits = adjC[(size_t)w * n + i];
            if (base <= i) {
                int sh = i - base + 1;
                bits = (sh >= 64) ? 0ull : (bits & (~0ull << sh));
            }
            while (bits) {
                int b = (int)__ffsll(bits) - 1; bits &= bits - 1;
                int j = base + b;                  // j > i
                int x = i, y = j;
                for (;;) {
                    int px = vp[x];
                    while (px != x) { int g = vp[px]; par[x] = g; x = g; px = vp[x]; }
                    int py = vp[y];
                    while (py != y) { int g = vp[py]; par[y] = g; y = g; py = vp[y]; }
                    if (x == y) break;
                    int hi = x > y ? x : y, lo = x > y ? y : x;
                    int old = atomicCAS(&par[hi], hi, lo);
                    if (old == hi) break;
                    x = lo; y = old;
                }
            }
        }
    }
    __syncthreads();
    for (int i = tid; i < n; i += 1024) {
        int x = i;
        while (par[x] != x) x = par[x];
        parentG[i] = x;
    }
}

// ---------------- Kernel 4: per-component exact greedy (block per root) -------
// seed(i) <=> no earlier neighbor of i is a seed; maxAdjSeed[j] = max-index
// adjacent seed (reference's last-writer-wins). Components are independent.
__global__ void compgreedy_kernel(const u64* __restrict__ adjC,
                                  const int* __restrict__ parentG,
                                  int* __restrict__ seedFlag,
                                  int* __restrict__ maxAdjSeed,
                                  int n, int words) {
    int root = blockIdx.x;
    if (parentG[root] != root) return;
    int lane = threadIdx.x;        // 64 = 1 wave
    __shared__ unsigned short mlist[4096];
    __shared__ u64 seedBitsS[64];
    __shared__ unsigned char dwl[64];
    __shared__ int ndwS;
    // gather members ascending (coalesced label scan + ballot compaction)
    int cnt = 0;
    for (int b2 = 0; b2 < n; b2 += 64) {
        int j = b2 + lane;
        bool mem = (j < n) && (parentG[j] == root);
        u64 bal = __ballot(mem);
        if (mem) {
            int pos = cnt + (int)__popcll(bal & ((1ull << lane) - 1ull));
            mlist[pos] = (unsigned short)j;
        }
        cnt += (int)__popcll(bal);
    }
    int m = cnt;
    __syncthreads();
    // serial greedy over members ascending; seed bitset distributed in registers
    u64 seedW = 0ull;              // lane l owns word l of the seed bitset
    for (int k = 0; k < m; ++k) {
        int v = mlist[k];
        int vw = v >> 6, vb = v & 63;
        u64 below = (lane < vw) ? ~0ull
                  : ((lane == vw) ? ((vb == 0) ? 0ull : ((1ull << vb) - 1ull)) : 0ull);
        u64 row = (lane < words) ? adjC[(size_t)lane * n + v] : 0ull;
        bool hit = (row & seedW & below) != 0ull;
        bool any = __ballot(hit) != 0ull;          // wave-uniform
        if (!any && lane == vw) seedW |= (1ull << vb);
    }
    seedBitsS[lane] = seedW;
    __syncthreads();
    // distinct word list of this component (mlist ascending -> grouped)
    if (lane == 0) {
        int c = 0, prev = -1;
        for (int k = 0; k < m; ++k) {
            int w = mlist[k] >> 6;
            if (w != prev) { dwl[c++] = (unsigned char)w; prev = w; }
        }
        ndwS = c;
    }
    __syncthreads();
    int ndw = ndwS;
    // per-member outputs (lane-parallel)
    for (int k = lane; k < m; k += 64) {
        int v = mlist[k];
        int best = -1;
        for (int d = ndw - 1; d >= 0; --d) {
            int w = dwl[d];
            u64 t = adjC[(size_t)w * n + v] & seedBitsS[w];
            if (t) { best = (w << 6) + 63 - (int)__clzll(t); break; }
        }
        seedFlag[v] = (int)((seedBitsS[v >> 6] >> (v & 63)) & 1ull);
        maxAdjSeed[v] = best;      // >=0 for every node (self if seed)
    }
}

// ---------------- Kernel 5: seed rank scan -> cids, seedList, indices ---------
__global__ void seedscan_kernel(const int* __restrict__ seedFlag,
                                const int* __restrict__ maxAdjSeed,
                                int* __restrict__ seedList,
                                int* __restrict__ indices,
                                int* __restrict__ nclust, int n) {
    __shared__ int rankS[4096];
    __shared__ int scanBuf[1024];
    int tid = threadIdx.x;  // 1024
    int per = (n + 1023) >> 10;  // 4
    int base = tid * per;
    int v[8]; int sum = 0;
    for (int k = 0; k < per && k < 8; ++k) {
        int j = base + k;
        int f = (j < n) ? seedFlag[j] : 0;
        v[k] = f; sum += f;
    }
    scanBuf[tid] = sum;
    __syncthreads();
    for (int o = 1; o < 1024; o <<= 1) {
        int val = scanBuf[tid];
        int add = (tid >= o) ? scanBuf[tid - o] : 0;
        __syncthreads();
        scanBuf[tid] = val + add;
        __syncthreads();
    }
    int run = scanBuf[tid] - sum;
    for (int k = 0; k < per && k < 8; ++k) {
        int j = base + k;
        if (j < n) { run += v[k]; rankS[j] = run; }
    }
    __syncthreads();
    for (int j = tid; j < n; j += 1024) {
        int ind = maxAdjSeed[j];
        indices[j] = (ind >= 0) ? rankS[ind] : 0;
        if (seedFlag[j]) seedList[rankS[j] - 1] = j;
    }
    if (tid == 1023) *nclust = scanBuf[1023];
}

// ---------------- Kernel 6: per-cluster fusion (seed-row member gather) -------
__global__ void fusion_kernel(const float* __restrict__ boxes,
                              const float* __restrict__ scores,
                              const int* __restrict__ indices,
                              const float* __restrict__ dir,
                              const int* __restrict__ seedListG,
                              const int* __restrict__ nclust,
                              const u64* __restrict__ adjC,
                              float* __restrict__ fused,
                              float* __restrict__ sfused,
                              int* __restrict__ validArr, int n, int words) {
    int i = blockIdx.x;           // output row; cluster id = i+1
    int lane = threadIdx.x;       // 64 = 1 wave
    int cid = i + 1;
    if (cid > *nclust) {
        if (lane < 7) fused[i*7+lane] = 0.0f;
        if (lane == 0) { sfused[i] = 0.0f; validArr[i] = 0; }
        return;
    }
    __shared__ unsigned short js[256];
    __shared__ float ms[256];
    int s = seedListG[i];
    u64 bits = (lane < words) ? adjC[(size_t)lane * n + s] : 0ull;
    // filter: keep only nodes whose final cluster is cid
    u64 keep = 0ull;
    u64 t = bits;
    while (t) {
        int b = (int)__ffsll(t) - 1;
        t &= t - 1;
        int node = (lane << 6) + b;
        if (indices[node] == cid) keep |= (1ull << b);
    }
    int cnt = __popcll(keep);
    int x = cnt;
    for (int o = 1; o < 64; o <<= 1) {
        int y = __shfl_up(x, o);
        if (lane >= o) x += y;
    }
    int excl = x - cnt;
    int m = __shfl(x, 63);
    int pos = excl;
    t = keep;
    while (t) {
        int b = (int)__ffsll(t) - 1;
        t &= t - 1;
        js[pos++] = (unsigned short)((lane << 6) + b);
    }
    __syncthreads();
    for (int k = lane; k < m; k += 64) ms[k] = scores[js[k]];
    __syncthreads();
    if (lane == 0) {
        if (m == 0) {
            for (int k = 0; k < 7; ++k) fused[i*7+k] = 0.0f;
            sfused[i] = 0.0f; validArr[i] = 0;
        } else {
            // s_sum and argmax (first occurrence of max; js ascending + strict >)
            float ssum = 0.0f, smax = -1e30f; int refj = js[0];
            for (int k = 0; k < m; ++k) {
                float sc = ms[k];
                ssum += sc;
                if (sc > smax) { smax = sc; refj = js[k]; }
            }
            float refdir = dir[refj];
            float denom = fmaxf(ssum, 1e-12f);
            float sgt = 0.0f;
            float cd0=0,cd1=0,cd2=0,cd3=0,cd4=0,cd5=0;
            for (int k = 0; k < m; ++k) {
                int j = js[k];
                float sc = ms[k];
                float d = fabsf(dir[j] - refdir);
                if (d > PI_F) d = TWO_PI_F - d;
                if (d > HALF_PI_F) sgt += sc;
                float wgt = sc / denom;
                cd0 += wgt * boxes[j*7+0];
                cd1 += wgt * boxes[j*7+1];
                cd2 += wgt * boxes[j*7+2];
                cd3 += wgt * boxes[j*7+3];
                cd4 += wgt * boxes[j*7+4];
                cd5 += wgt * boxes[j*7+5];
            }
            float sle = ssum - sgt;
            bool flipGt = (sgt <= sle);
            float ssin = 0.0f, scos = 0.0f;
            for (int k = 0; k < m; ++k) {
                int j = js[k];
                float sc = ms[k];
                float dj = dir[j];
                float d = fabsf(dj - refdir);
                if (d > PI_F) d = TWO_PI_F - d;
                bool gt = d > HALF_PI_F;
                bool flip = flipGt ? gt : !gt;
                float adj_d = limit_period_f(dj + (flip ? PI_F : 0.0f));
                float wgt = sc / denom;
                ssin += sinf(adj_d) * wgt;
                scos += cosf(adj_d) * wgt;
            }
            float theta = atan2f(ssin, scos);
            // s_fused: sort member scores descending, sum s_k^(k+1)
            for (int k = 1; k < m; ++k) {
                float key = ms[k]; int p = k - 1;
                while (p >= 0 && ms[p] < key) { ms[p+1] = ms[p]; --p; }
                ms[p+1] = key;
            }
            float sf = 0.0f;
            for (int k = 0; k < m; ++k) sf += powf(ms[k], (float)(k+1));
            sf = fminf(sf, 1.0f);
            // corners range check
            float c_ = cosf(theta), s_ = sinf(theta);
            float wdim = cd4, ldim = cd5;
            const float xs[4]  = {0.5f, 0.5f, -0.5f, -0.5f};
            const float ys_[4] = {-0.5f, 0.5f, 0.5f, -0.5f};
            bool inr = true;
            for (int c = 0; c < 4; ++c) {
                float cx = ldim * xs[c], cy = wdim * ys_[c];
                float rx = cx*c_ - cy*s_ + cd0;
                float ry = cx*s_ + cy*c_ + cd1;
                inr = inr && (rx > -140.8f) && (rx < 140.8f) && (ry > -40.0f) && (ry < 40.0f);
            }
            fused[i*7+0]=cd0; fused[i*7+1]=cd1; fused[i*7+2]=cd2;
            fused[i*7+3]=cd3; fused[i*7+4]=cd4; fused[i*7+5]=cd5;
            fused[i*7+6]=theta;
            sfused[i] = sf;
            validArr[i] = inr ? 1 : 0;
        }
    }
}

// ---------------- Kernel 7: cumsum + gated output writes ----------------
__global__ void finalize_kernel(const float* __restrict__ fused,
                                const float* __restrict__ sfused,
                                const int* __restrict__ validArr,
                                const int* __restrict__ indices,
                                float* __restrict__ out, int n) {
    __shared__ int newidS[4096];
    __shared__ unsigned char validS[4096];
    __shared__ int scanBuf[1024];
    int tid = threadIdx.x;  // 1024
    int per = (n + 1023) >> 10;  // 4
    int base = tid * per;
    int v[8];
    int sum = 0;
    for (int k = 0; k < per && k < 8; ++k) {
        int j = base + k;
        int vv = (j < n) ? validArr[j] : 0;
        v[k] = vv; sum += vv;
    }
    scanBuf[tid] = sum;
    __syncthreads();
    for (int o = 1; o < 1024; o <<= 1) {
        int val = scanBuf[tid];
        int add = (tid >= o) ? scanBuf[tid - o] : 0;
        __syncthreads();
        scanBuf[tid] = val + add;
        __syncthreads();
    }
    int run = scanBuf[tid] - sum;
    for (int k = 0; k < per && k < 8; ++k) {
        int j = base + k;
        if (j < n) { run += v[k]; newidS[j] = run; validS[j] = (unsigned char)v[k]; }
    }
    __syncthreads();
    float* boxesO  = out;
    float* scoresO = out + (size_t)7*n;
    float* validO  = out + (size_t)8*n;
    float* idxO    = out + (size_t)9*n;
    for (int j = tid; j < n; j += 1024) {
        int vv = validS[j];
        #pragma unroll
        for (int k = 0; k < 7; ++k)
            boxesO[j*7+k] = vv ? fused[j*7+k] : 0.0f;
        scoresO[j] = vv ? sfused[j] : 0.0f;
        validO[j]  = vv ? 1.0f : 0.0f;
        int ind = indices[j];
        int safe = ind - 1; if (safe < 0) safe = 0;
        bool nv = (ind > 0) && (validS[safe] != 0);
        idxO[j] = nv ? (float)newidS[safe] : 0.0f;
    }
}

extern "C" void kernel_launch(void* const* d_in, const int* in_sizes, int n_in,
                              void* d_out, int out_size, void* d_ws, size_t ws_size,
                              hipStream_t stream) {
    const float* boxes  = (const float*)d_in[0];
    const float* scores = (const float*)d_in[1];
    int n = in_sizes[0] / 7;           // 4096
    int words = (n + 63) >> 6;         // 64

    char* ws = (char*)d_ws;
    size_t nf = (size_t)n * sizeof(float);
    size_t off = 0;
    float* lox = (float*)(ws + off); off += nf;
    float* loy = (float*)(ws + off); off += nf;
    float* loz = (float*)(ws + off); off += nf;
    float* hix = (float*)(ws + off); off += nf;
    float* hiy = (float*)(ws + off); off += nf;
    float* hiz = (float*)(ws + off); off += nf;
    float* vol = (float*)(ws + off); off += nf;
    float* dir = (float*)(ws + off); off += nf;
    off = (off + 7) & ~(size_t)7;
    u64* adjC = (u64*)(ws + off);
    off += (size_t)n * words * sizeof(u64);
    int* parentG   = (int*)(ws + off); off += (size_t)n * sizeof(int);
    int* seedFlag  = (int*)(ws + off); off += (size_t)n * sizeof(int);
    int* maxAdjSeed= (int*)(ws + off); off += (size_t)n * sizeof(int);
    int* seedList  = (int*)(ws + off); off += (size_t)n * sizeof(int);
    int* indices   = (int*)(ws + off); off += (size_t)n * sizeof(int);
    float* fused   = (float*)(ws + off); off += (size_t)n * 7 * sizeof(float);
    float* sfused  = (float*)(ws + off); off += nf;
    int* validArr  = (int*)(ws + off); off += (size_t)n * sizeof(int);
    int* nclust    = (int*)(ws + off); off += sizeof(int);

    prep_kernel<<<(n + 255) / 256, 256, 0, stream>>>(boxes, n, lox, loy, loz,
                                                     hix, hiy, hiz, vol, dir);
    adj_kernel<<<(n + ITILE - 1) / ITILE, 256, 0, stream>>>(lox, loy, loz, hix, hiy, hiz,
                                                            vol, adjC, n, words);
    ccuf_kernel<<<1, 1024, 0, stream>>>(adjC, parentG, n, words);
    compgreedy_kernel<<<n, 64, 0, stream>>>(adjC, parentG, seedFlag, maxAdjSeed, n, words);
    seedscan_kernel<<<1, 1024, 0, stream>>>(seedFlag, maxAdjSeed, seedList, indices, nclust, n);
    fusion_kernel<<<n, 64, 0, stream>>>(boxes, scores, indices, dir, seedList, nclust,
                                        adjC, fused, sfused, validArr, n, words);
    finalize_kernel<<<1, 1024, 0, stream>>>(fused, sfused, validArr, indices,
                                            (float*)d_out, n);
}

// Round 7
// 191.270 us; speedup vs baseline: 2.1353x; 1.5226x over previous
//
#include <hip/hip_runtime.h>
#include <math.h>

#define PI_F      3.141592653f
#define TWO_PI_F  6.283185306f
#define HALF_PI_F 1.5707963265f
#define IOU_THR_F 0.1f
#define ITILE     16
#define NSWEEP    8

typedef unsigned long long u64;

__device__ __forceinline__ float limit_period_f(float v) {
    return v - floorf(v / TWO_PI_F + 0.5f) * TWO_PI_F;
}

__device__ __forceinline__ u64 shfl_u64(u64 v, int src) {
    unsigned int lo = (unsigned int)(v & 0xffffffffull);
    unsigned int hi = (unsigned int)(v >> 32);
    lo = __shfl((int)lo, src);
    hi = __shfl((int)hi, src);
    return ((u64)hi << 32) | (u64)lo;
}

// ---------------- Kernel 1: adjacency bit-matrix (prep folded in) -------------
// adjC[(size_t)w * n + i] = word w of row i. Block 0 also inits S/R bitsets.
__global__ void adj_kernel(const float* __restrict__ boxes,
                           u64* __restrict__ adjC,
                           u64* __restrict__ S, u64* __restrict__ R,
                           int n, int words) {
    __shared__ float iS[7][ITILE];
    int ib = blockIdx.x * ITILE;
    int tid = threadIdx.x;              // 256 = 4 waves
    if (blockIdx.x == 0 && tid < 64) {
        S[tid] = 0ull;
        int base = tid << 6;
        int vb = n - base;
        u64 valid = (vb >= 64) ? ~0ull : ((vb <= 0) ? 0ull : ((1ull << vb) - 1ull));
        R[tid] = ~valid;                // invalid tail = resolved nonseed
    }
    if (tid < ITILE) {
        int i = ib + tid;
        if (i < n) {
            float b0 = boxes[i*7+0], b1 = boxes[i*7+1], b2 = boxes[i*7+2];
            float b3 = boxes[i*7+3], b4 = boxes[i*7+4], b5 = boxes[i*7+5];
            iS[0][tid] = b0 - b5*0.5f;  iS[3][tid] = b0 + b5*0.5f;
            iS[1][tid] = b1 - b4*0.5f;  iS[4][tid] = b1 + b4*0.5f;
            iS[2][tid] = b2 - b3*0.5f;  iS[5][tid] = b2 + b3*0.5f;
            iS[6][tid] = (b5*b4)*b3;
        }
    }
    __syncthreads();
    int lane = tid & 63, wv = tid >> 6;
    int ntile = (n + 255) >> 8;
    for (int t = 0; t < ntile; ++t) {
        int j = (t << 8) + tid;
        bool jin = j < n;
        float ljx=0, ljy=0, ljz=0, hjx=0, hjy=0, hjz=0, vj=0;
        if (jin) {
            float b0 = boxes[j*7+0], b1 = boxes[j*7+1], b2 = boxes[j*7+2];
            float b3 = boxes[j*7+3], b4 = boxes[j*7+4], b5 = boxes[j*7+5];
            ljx = b0 - b5*0.5f;  hjx = b0 + b5*0.5f;
            ljy = b1 - b4*0.5f;  hjy = b1 + b4*0.5f;
            ljz = b2 - b3*0.5f;  hjz = b2 + b3*0.5f;
            vj  = (b5*b4)*b3;
        }
        int wj = (t << 2) + wv;         // uniform across the wave
        u64 myMask = 0;
        for (int ii = 0; ii < ITILE; ++ii) {
            bool pred = false;
            if (jin && (ib + ii) < n) {
                float ix = fminf(iS[3][ii], hjx) - fmaxf(iS[0][ii], ljx); ix = fmaxf(ix, 0.0f);
                float iy = fminf(iS[4][ii], hjy) - fmaxf(iS[1][ii], ljy); iy = fmaxf(iy, 0.0f);
                float iz = fminf(iS[5][ii], hjz) - fmaxf(iS[2][ii], ljz); iz = fmaxf(iz, 0.0f);
                float inter = (ix*iy)*iz;
                float u = fmaxf(iS[6][ii] + vj - inter, 1e-8f);
                pred = (inter / u) > IOU_THR_F;
            }
            u64 mk = __ballot(pred);
            if (lane == ii) myMask = mk;
        }
        if (lane < ITILE && (ib + lane) < n && wj < words)
            adjC[(size_t)wj * n + (ib + lane)] = myMask;
    }
}

// ---------------- Kernel 2: greedy-MIS sweep (one 64-lane block per word) -----
// seed(i) <=> no earlier neighbor of i is a seed. Each sweep resolves every
// node whose earlier cross-word deps are resolved; exact in-word greedy.
// S/R monotone in global; inter-launch coherence gives Gauss-Seidel progress.
__global__ void sweep_kernel(const u64* __restrict__ adjC,
                             u64* __restrict__ S, u64* __restrict__ R,
                             int n, int words) {
    int w = blockIdx.x;
    int lane = threadIdx.x;        // 64
    u64 S_reg = S[lane];
    u64 R_reg = R[lane];
    u64 Rw = shfl_u64(R_reg, w);
    int base = w << 6;
    int vb = n - base;
    u64 valid = (vb >= 64) ? ~0ull : ((vb <= 0) ? 0ull : ((1ull << vb) - 1ull));
    u64 unknownIn = valid & ~Rw;
    if (unknownIn == 0ull) return;          // word fully resolved
    int i = base + lane;
    u64 Adiag = (i < n) ? adjC[(size_t)w * n + i] : 0ull;
    // scan earlier words: any-seed / any-unknown among earlier neighbors
    u64 seenAcc = 0ull, unkAcc = 0ull;
    for (int w2 = 0; w2 < w; ++w2) {
        u64 row = (i < n) ? adjC[(size_t)w2 * n + i] : 0ull;
        u64 s2 = shfl_u64(S_reg, w2);
        u64 r2 = shfl_u64(R_reg, w2);
        seenAcc |= row & s2;
        unkAcc  |= row & ~r2;
    }
    u64 E_seen  = __ballot(seenAcc != 0ull);
    u64 Unk_ext = __ballot(unkAcc  != 0ull);
    // exact in-word greedy over unresolved bits, ascending (wave-uniform)
    u64 newSeed = shfl_u64(S_reg, w);
    u64 newRes  = Rw;
    u64 pending = unknownIn;
    while (pending) {
        int b = (int)__ffsll(pending) - 1;
        pending &= pending - 1;
        u64 rowb = shfl_u64(Adiag, b);
        u64 below = b ? ((1ull << b) - 1ull) : 0ull;
        u64 earlier = rowb & below;
        u64 bit = 1ull << b;
        bool eSeen = (E_seen >> b) & 1ull;
        bool eUnk  = (Unk_ext >> b) & 1ull;
        if (eSeen || (earlier & newSeed)) {
            newRes |= bit;                          // nonseed
        } else if (eUnk || (earlier & ~newRes)) {
            // blocked: unresolved earlier neighbor exists
        } else {
            newSeed |= bit; newRes |= bit;          // seed
        }
    }
    if (lane == 0) { S[w] = newSeed; R[w] = newRes; }
}

// ---------------- Kernel 3: indices + seedList + nclust -----------------------
// indices[j] = rank of max-index adjacent seed (last-writer-wins semantics).
__global__ void indices_kernel(const u64* __restrict__ adjC,
                               const u64* __restrict__ S,
                               int* __restrict__ indices,
                               int* __restrict__ seedList,
                               int* __restrict__ nclust, int n, int words) {
    __shared__ u64 smS[64];
    __shared__ int wsS[64];
    int tid = threadIdx.x;  // 256
    if (tid < 64) {
        u64 s = (tid < words) ? S[tid] : 0ull;
        smS[tid] = s;
        int pc = (int)__popcll(s);
        int x = pc;
        for (int o = 1; o < 64; o <<= 1) {
            int y = __shfl_up(x, o);
            if (tid >= o) x += y;
        }
        wsS[tid] = x - pc;              // exclusive scan
        if (blockIdx.x == 0 && tid == 63) *nclust = x;
    }
    __syncthreads();
    int j = blockIdx.x * blockDim.x + tid;
    if (j >= n) return;
    int idx = 0;
    for (int w = 0; w < words; ++w) {
        u64 m = adjC[(size_t)w * n + j] & smS[w];   // coalesced, independent
        if (m) {
            int b = 63 - (int)__clzll(m);
            u64 incl = (b >= 63) ? ~0ull : ((2ull << b) - 1ull);
            idx = wsS[w] + (int)__popcll(smS[w] & incl);  // 1-based cid
        }
    }
    indices[j] = idx;
    int wj = j >> 6, bj = j & 63;
    if ((smS[wj] >> bj) & 1ull) {
        int rank = wsS[wj] + (int)__popcll(smS[wj] & ((bj ? ((1ull << bj) - 1ull) : 0ull))) + 1;
        seedList[rank - 1] = j;
    }
}

// ---------------- Kernel 4: per-cluster fusion (seed-row member gather) -------
__global__ void fusion_kernel(const float* __restrict__ boxes,
                              const float* __restrict__ scores,
                              const int* __restrict__ indices,
                              const int* __restrict__ seedListG,
                              const int* __restrict__ nclust,
                              const u64* __restrict__ adjC,
                              float* __restrict__ fused,
                              float* __restrict__ sfused,
                              int* __restrict__ validArr, int n, int words) {
    int i = blockIdx.x;           // output row; cluster id = i+1
    int lane = threadIdx.x;       // 64 = 1 wave
    int cid = i + 1;
    if (cid > *nclust) {
        if (lane < 7) fused[i*7+lane] = 0.0f;
        if (lane == 0) { sfused[i] = 0.0f; validArr[i] = 0; }
        return;
    }
    __shared__ unsigned short js[256];
    __shared__ float ms[256];
    __shared__ float ds[256];
    int s = seedListG[i];
    u64 bits = (lane < words) ? adjC[(size_t)lane * n + s] : 0ull;
    // filter: keep only nodes whose final cluster is cid
    u64 keep = 0ull;
    u64 t = bits;
    while (t) {
        int b = (int)__ffsll(t) - 1;
        t &= t - 1;
        int node = (lane << 6) + b;
        if (indices[node] == cid) keep |= (1ull << b);
    }
    int cnt = __popcll(keep);
    int x = cnt;
    for (int o = 1; o < 64; o <<= 1) {
        int y = __shfl_up(x, o);
        if (lane >= o) x += y;
    }
    int excl = x - cnt;
    int m = __shfl(x, 63);
    int pos = excl;
    t = keep;
    while (t) {
        int b = (int)__ffsll(t) - 1;
        t &= t - 1;
        js[pos++] = (unsigned short)((lane << 6) + b);
    }
    __syncthreads();
    for (int k = lane; k < m; k += 64) {
        int j = js[k];
        ms[k] = scores[j];
        ds[k] = limit_period_f(boxes[j*7+6]);
    }
    __syncthreads();
    if (lane == 0) {
        if (m == 0) {
            for (int k = 0; k < 7; ++k) fused[i*7+k] = 0.0f;
            sfused[i] = 0.0f; validArr[i] = 0;
        } else {
            // s_sum and argmax (first occurrence of max; js ascending + strict >)
            float ssum = 0.0f, smax = -1e30f; int kref = 0;
            for (int k = 0; k < m; ++k) {
                float sc = ms[k];
                ssum += sc;
                if (sc > smax) { smax = sc; kref = k; }
            }
            float refdir = ds[kref];
            float denom = fmaxf(ssum, 1e-12f);
            float sgt = 0.0f;
            float cd0=0,cd1=0,cd2=0,cd3=0,cd4=0,cd5=0;
            for (int k = 0; k < m; ++k) {
                int j = js[k];
                float sc = ms[k];
                float d = fabsf(ds[k] - refdir);
                if (d > PI_F) d = TWO_PI_F - d;
                if (d > HALF_PI_F) sgt += sc;
                float wgt = sc / denom;
                cd0 += wgt * boxes[j*7+0];
                cd1 += wgt * boxes[j*7+1];
                cd2 += wgt * boxes[j*7+2];
                cd3 += wgt * boxes[j*7+3];
                cd4 += wgt * boxes[j*7+4];
                cd5 += wgt * boxes[j*7+5];
            }
            float sle = ssum - sgt;
            bool flipGt = (sgt <= sle);
            float ssin = 0.0f, scos = 0.0f;
            for (int k = 0; k < m; ++k) {
                float sc = ms[k];
                float dj = ds[k];
                float d = fabsf(dj - refdir);
                if (d > PI_F) d = TWO_PI_F - d;
                bool gt = d > HALF_PI_F;
                bool flip = flipGt ? gt : !gt;
                float adj_d = limit_period_f(dj + (flip ? PI_F : 0.0f));
                float wgt = sc / denom;
                ssin += sinf(adj_d) * wgt;
                scos += cosf(adj_d) * wgt;
            }
            float theta = atan2f(ssin, scos);
            // s_fused: sort member scores descending, sum s_k^(k+1)
            for (int k = 1; k < m; ++k) {
                float key = ms[k]; int p = k - 1;
                while (p >= 0 && ms[p] < key) { ms[p+1] = ms[p]; --p; }
                ms[p+1] = key;
            }
            float sf = 0.0f;
            for (int k = 0; k < m; ++k) sf += powf(ms[k], (float)(k+1));
            sf = fminf(sf, 1.0f);
            // corners range check
            float c_ = cosf(theta), s_ = sinf(theta);
            float wdim = cd4, ldim = cd5;
            const float xs[4]  = {0.5f, 0.5f, -0.5f, -0.5f};
            const float ys_[4] = {-0.5f, 0.5f, 0.5f, -0.5f};
            bool inr = true;
            for (int c = 0; c < 4; ++c) {
                float cx = ldim * xs[c], cy = wdim * ys_[c];
                float rx = cx*c_ - cy*s_ + cd0;
                float ry = cx*s_ + cy*c_ + cd1;
                inr = inr && (rx > -140.8f) && (rx < 140.8f) && (ry > -40.0f) && (ry < 40.0f);
            }
            fused[i*7+0]=cd0; fused[i*7+1]=cd1; fused[i*7+2]=cd2;
            fused[i*7+3]=cd3; fused[i*7+4]=cd4; fused[i*7+5]=cd5;
            fused[i*7+6]=theta;
            sfused[i] = sf;
            validArr[i] = inr ? 1 : 0;
        }
    }
}

// ---------------- Kernel 5: cumsum + gated output writes ----------------
__global__ void finalize_kernel(const float* __restrict__ fused,
                                const float* __restrict__ sfused,
                                const int* __restrict__ validArr,
                                const int* __restrict__ indices,
                                float* __restrict__ out, int n) {
    __shared__ int newidS[4096];
    __shared__ unsigned char validS[4096];
    __shared__ int scanBuf[1024];
    int tid = threadIdx.x;  // 1024
    int per = (n + 1023) >> 10;  // 4
    int base = tid * per;
    int v[8];
    int sum = 0;
    for (int k = 0; k < per && k < 8; ++k) {
        int j = base + k;
        int vv = (j < n) ? validArr[j] : 0;
        v[k] = vv; sum += vv;
    }
    scanBuf[tid] = sum;
    __syncthreads();
    for (int o = 1; o < 1024; o <<= 1) {
        int val = scanBuf[tid];
        int add = (tid >= o) ? scanBuf[tid - o] : 0;
        __syncthreads();
        scanBuf[tid] = val + add;
        __syncthreads();
    }
    int run = scanBuf[tid] - sum;
    for (int k = 0; k < per && k < 8; ++k) {
        int j = base + k;
        if (j < n) { run += v[k]; newidS[j] = run; validS[j] = (unsigned char)v[k]; }
    }
    __syncthreads();
    float* boxesO  = out;
    float* scoresO = out + (size_t)7*n;
    float* validO  = out + (size_t)8*n;
    float* idxO    = out + (size_t)9*n;
    for (int j = tid; j < n; j += 1024) {
        int vv = validS[j];
        #pragma unroll
        for (int k = 0; k < 7; ++k)
            boxesO[j*7+k] = vv ? fused[j*7+k] : 0.0f;
        scoresO[j] = vv ? sfused[j] : 0.0f;
        validO[j]  = vv ? 1.0f : 0.0f;
        int ind = indices[j];
        int safe = ind - 1; if (safe < 0) safe = 0;
        bool nv = (ind > 0) && (validS[safe] != 0);
        idxO[j] = nv ? (float)newidS[safe] : 0.0f;
    }
}

extern "C" void kernel_launch(void* const* d_in, const int* in_sizes, int n_in,
                              void* d_out, int out_size, void* d_ws, size_t ws_size,
                              hipStream_t stream) {
    const float* boxes  = (const float*)d_in[0];
    const float* scores = (const float*)d_in[1];
    int n = in_sizes[0] / 7;           // 4096
    int words = (n + 63) >> 6;         // 64

    char* ws = (char*)d_ws;
    size_t off = 0;
    u64* adjC = (u64*)(ws + off);
    off += (size_t)n * words * sizeof(u64);
    u64* S = (u64*)(ws + off); off += 64 * sizeof(u64);
    u64* R = (u64*)(ws + off); off += 64 * sizeof(u64);
    int* seedList = (int*)(ws + off); off += (size_t)n * sizeof(int);
    int* indices  = (int*)(ws + off); off += (size_t)n * sizeof(int);
    float* fused  = (float*)(ws + off); off += (size_t)n * 7 * sizeof(float);
    float* sfused = (float*)(ws + off); off += (size_t)n * sizeof(float);
    int* validArr = (int*)(ws + off); off += (size_t)n * sizeof(int);
    int* nclust   = (int*)(ws + off); off += sizeof(int);

    adj_kernel<<<(n + ITILE - 1) / ITILE, 256, 0, stream>>>(boxes, adjC, S, R, n, words);
    for (int s2 = 0; s2 < NSWEEP; ++s2)
        sweep_kernel<<<words, 64, 0, stream>>>(adjC, S, R, n, words);
    indices_kernel<<<(n + 255) / 256, 256, 0, stream>>>(adjC, S, indices, seedList,
                                                        nclust, n, words);
    fusion_kernel<<<n, 64, 0, stream>>>(boxes, scores, indices, seedList, nclust,
                                        adjC, fused, sfused, validArr, n, words);
    finalize_kernel<<<1, 1024, 0, stream>>>(fused, sfused, validArr, indices,
                                            (float*)d_out, n);
}